// Round 15
// baseline (611.102 us; speedup 1.0000x reference)
//
#include <hip/hip_runtime.h>
#include <hip/hip_bf16.h>
#include <cstdint>

// ---------------------------------------------------------------------------
// 3-layer GCN on MI355X — bf16 feature pipeline, f32 accumulate.
//   memset : cnt+ovfn = 0, A zero-row = 0   (hipMemsetAsync, capture-safe)
//   k_cntprep: INTERLEAVED %4 roles —
//     rem0: atomic pass pos[e]=atomicAdd(cnt[dst[e]])   (the 67us wall)
//     rem1/2: prep x->bf16 xb | W0/1/2->Wt bf16
//     rem3: residual GEMM R = bf16(x@Wr+br), f32-x direct (R19 path) with
//           self-staged Wr (f32 -> transposed bf16 LDS) — zero intra-dispatch
//           deps, rides the wall's idle pipes.
//   k_scat : aux blocks FIRST (dinv + epk pads), then atomic-free scatter.
//   k_gemm : A = bf16(dinv*(xb@W0)); then agg/gemm/agg/gemm/agg.
//
// Measured walls (closed): atomic RMW ~67us memory-side (scope/replication
// no-op R10/11; scatter-in-pass worse R15) but pipes <1% busy -> hide work
// under it (R22/R23: prep hidden, 83->70 via %-interleave co-residency).
// k_agg ~65us = real ~3.9-4.0 TB/s gather ceiling (R16 pinned at 4.0 while
// moving 2.3x bytes; R12 +20% insts = no change) — FINAL form. GEMM: LDS
// staging mandatory (R17); bf16 xb input for the dinv-prescaled GEMMs (R19)
// — the f32-x path is used ONLY where hidden under the wall.
// R24 (this): gemmR as 4th interleaved role in cntprep (reads f32 x + f32 Wr
// directly -> no dependency on prep outputs); gemmRA -> plain gemm0.
// NOTE: LDS-GEMM + atomics in one dispatch = the R13/R14-era shape; round-1
// precedent (identical code fail->pass) says those were pool flake. If the
// container dies: pattern confirmed fatal, revert to R23 and declare.
// ---------------------------------------------------------------------------

#define WS_ALIGN(x) (((x) + 255) & ~(size_t)255)

typedef __bf16 bf16x8 __attribute__((ext_vector_type(8)));
typedef float  floatx4 __attribute__((ext_vector_type(4)));

static __device__ __forceinline__ float bf_lo(unsigned u) {
  return __builtin_bit_cast(float, u << 16);
}
static __device__ __forceinline__ float bf_hi(unsigned u) {
  return __builtin_bit_cast(float, u & 0xffff0000u);
}
// f32 -> bf16 round-to-nearest-even (finite inputs only)
static __device__ __forceinline__ unsigned short f2bs(float f) {
  unsigned u = __builtin_bit_cast(unsigned, f);
  return (unsigned short)((u + 0x7fffu + ((u >> 16) & 1u)) >> 16);
}
static __device__ __forceinline__ unsigned pack2(float a, float b) {
  return (unsigned)f2bs(a) | ((unsigned)f2bs(b) << 16);
}

// ---------------- bf16 MFMA GEMM tile (proven body, param'd by vt) ---------
// Wt staged in 32 KB LDS (R17: 256B-lane-stride B-frags must not hit VMEM).
// Layouts (verified, learn_hip m89/m120): A[m=lane&15][k=quad*8+j],
// B[k=quad*8+j][n=lane&15], C/D col=lane&15 row=quad*4+reg.
static __device__ __forceinline__ void gemm_tile(
    int vt, const unsigned short* __restrict__ Xb,
    const unsigned short* sWt,
    const float* __restrict__ bias, const float* __restrict__ dv,
    unsigned short* __restrict__ Y, int n) {
  const int lane = threadIdx.x & 63;
  const int wave = threadIdx.x >> 6;
  const int l15 = lane & 15;
  const int quad = lane >> 4;
  const int rbase = vt * 64 + wave * 16;

  const bf16x8* sW8 = (const bf16x8*)sWt;
  bf16x8 b[8][4];
#pragma unroll
  for (int ct = 0; ct < 8; ct++)
#pragma unroll
    for (int kc = 0; kc < 4; kc++)
      b[ct][kc] = sW8[(ct * 16 + l15) * 16 + kc * 4 + quad];

  int row = rbase + l15;
  row = row < n ? row : n - 1;
  const bf16x8* X8 = (const bf16x8*)Xb;
  bf16x8 a[4];
#pragma unroll
  for (int kc = 0; kc < 4; kc++)
    a[kc] = X8[(size_t)row * 16 + kc * 4 + quad];

  floatx4 acc[8];
#pragma unroll
  for (int ct = 0; ct < 8; ct++) acc[ct] = (floatx4){0.f, 0.f, 0.f, 0.f};

#pragma unroll
  for (int kc = 0; kc < 4; kc++)
#pragma unroll
    for (int ct = 0; ct < 8; ct++)
      acc[ct] = __builtin_amdgcn_mfma_f32_16x16x32_bf16(a[kc], b[ct][kc], acc[ct], 0, 0, 0);

  const int orow = rbase + quad * 4;
  float4 dvv;
  dvv.x = 1.f; dvv.y = 1.f; dvv.z = 1.f; dvv.w = 1.f;
  if (dv) {
    int od = orow < n ? orow : 0;      // orow is 4-aligned, n % 4 == 0
    dvv = *(const float4*)(dv + od);
  }
#pragma unroll
  for (int ct = 0; ct < 8; ct++) {
    const int c = ct * 16 + l15;
    const float bv = bias ? bias[c] : 0.f;
#pragma unroll
    for (int r4 = 0; r4 < 4; r4++) {
      int r = orow + r4;
      float dm = r4 == 0 ? dvv.x : r4 == 1 ? dvv.y : r4 == 2 ? dvv.z : dvv.w;
      if (r < n) Y[(size_t)r * 128 + c] = f2bs(acc[ct][r4] * dm + bv);
    }
  }
}

// f32-x variant (R19-verified A-path): converts x rows in-register. Used only
// where the extra gather-pattern f32 reads are hidden under the atomic wall.
static __device__ __forceinline__ void gemm_tile_f32x(
    int vt, const float* __restrict__ Xf, const unsigned short* sWt,
    const float* __restrict__ bias, unsigned short* __restrict__ Y, int n) {
  const int lane = threadIdx.x & 63;
  const int wave = threadIdx.x >> 6;
  const int l15 = lane & 15;
  const int quad = lane >> 4;
  const int rbase = vt * 64 + wave * 16;

  const bf16x8* sW8 = (const bf16x8*)sWt;
  bf16x8 b[8][4];
#pragma unroll
  for (int ct = 0; ct < 8; ct++)
#pragma unroll
    for (int kc = 0; kc < 4; kc++)
      b[ct][kc] = sW8[(ct * 16 + l15) * 16 + kc * 4 + quad];

  int row = rbase + l15;
  row = row < n ? row : n - 1;
  const float4* X4 = (const float4*)Xf;
  bf16x8 a[4];
#pragma unroll
  for (int kc = 0; kc < 4; kc++) {
    float4 f0 = X4[(size_t)row * 32 + (kc * 4 + quad) * 2];
    float4 f1 = X4[(size_t)row * 32 + (kc * 4 + quad) * 2 + 1];
    uint4 u;
    u.x = pack2(f0.x, f0.y); u.y = pack2(f0.z, f0.w);
    u.z = pack2(f1.x, f1.y); u.w = pack2(f1.z, f1.w);
    a[kc] = __builtin_bit_cast(bf16x8, u);
  }

  floatx4 acc[8];
#pragma unroll
  for (int ct = 0; ct < 8; ct++) acc[ct] = (floatx4){0.f, 0.f, 0.f, 0.f};

#pragma unroll
  for (int kc = 0; kc < 4; kc++)
#pragma unroll
    for (int ct = 0; ct < 8; ct++)
      acc[ct] = __builtin_amdgcn_mfma_f32_16x16x32_bf16(a[kc], b[ct][kc], acc[ct], 0, 0, 0);

  const int orow = rbase + quad * 4;
#pragma unroll
  for (int ct = 0; ct < 8; ct++) {
    const int c = ct * 16 + l15;
    const float bv = bias[c];
#pragma unroll
    for (int r4 = 0; r4 < 4; r4++) {
      int r = orow + r4;
      if (r < n) Y[(size_t)r * 128 + c] = f2bs(acc[ct][r4] + bv);
    }
  }
}

static __device__ __forceinline__ void stage_w(const unsigned short* Wm,
                                               unsigned short* sWt) {
  const uint4* s4 = (const uint4*)Wm;
  uint4* d4 = (uint4*)sWt;
  for (int i = threadIdx.x; i < 2048; i += 256) d4[i] = s4[i];
  __syncthreads();
}

// ---- fused + INTERLEAVED %4: atomic | prep | prep | residual GEMM ---------
// rem0 -> atomic block vc; rem1/2 -> prep block 2*vc+rem-1; rem3 -> gemmR
// tile vc. Every CU holds a mix from t=0 (R23 lesson: range-split serializes;
// index-interleave co-resides). gemmR reads f32 x and self-stages f32 Wr ->
// transposed bf16 LDS (coalesced LDS writes, L2-absorbed strided reads of a
// hot 64 KB matrix) — ZERO dependency on prep outputs in this dispatch.
__global__ __launch_bounds__(256, 2) void k_cntprep(
    const int* __restrict__ dstv, int E, int eb,
    int* __restrict__ cnt, int* __restrict__ pos,
    const float* __restrict__ x, unsigned* __restrict__ xb,
    int n4, int xbn,
    const float* __restrict__ W0, const float* __restrict__ W1,
    const float* __restrict__ W2, unsigned short* __restrict__ Wt,
    const float* __restrict__ Wr, const float* __restrict__ brs,
    unsigned short* __restrict__ R, int gb, int n) {
  __shared__ unsigned short sWt[128 * 128];
  int g = blockIdx.x;
  int vc = g >> 2, rem = g & 3;
  if (rem == 0) {
    if (vc < eb) {
      int e = vc * 256 + threadIdx.x;
      if (e < E) pos[e] = atomicAdd(&cnt[dstv[e]], 1);
    }
  } else if (rem < 3) {
    int p = 2 * vc + rem - 1;
    if (p < xbn) {
      int i = p * 256 + threadIdx.x;
      if (i < n4) {
        float4 v = ((const float4*)x)[i];
        uint2 o;
        o.x = pack2(v.x, v.y);
        o.y = pack2(v.z, v.w);
        ((uint2*)xb)[i] = o;
      }
    } else if (p < xbn + 192) {
      int wv = p - xbn;               // 0..191 (W0,W1,W2 only)
      int mat = wv >> 6, blk = wv & 63;
      const float* W = mat == 0 ? W0 : mat == 1 ? W1 : W2;
      unsigned short* T = Wt + (size_t)mat * 16384;
      int i = blk * 256 + threadIdx.x;  // i = k*128 + nn, coalesced read
      int k = i >> 7, nn = i & 127;
      T[nn * 128 + k] = f2bs(W[i]);
    }
  } else {
    if (vc < gb) {
      // self-stage Wr: f32 [k][nn] -> bf16 transposed [nn][k] in LDS.
      // LDS writes consecutive (conflict-free); global reads stride-512B
      // hit the L2-hot 64 KB Wr.
      for (int j = (int)threadIdx.x; j < 16384; j += 256) {
        int nn = j >> 7, k = j & 127;
        sWt[j] = f2bs(Wr[k * 128 + nn]);
      }
      __syncthreads();
      gemm_tile_f32x(vc, x, sWt, brs, R, n);
    }
  }
}

// ---- fused: aux (dinv + epk pads) FIRST, then atomic-free scatter ---------
__global__ void k_scat(const int* __restrict__ srcv, const int* __restrict__ dstv,
                       const int* __restrict__ pos, int E, int nb,
                       const int* __restrict__ cnt, float* __restrict__ dinv,
                       int* __restrict__ epk, int2* __restrict__ ovf,
                       int* __restrict__ ovfn, int n) {
  int b = blockIdx.x;
  if (b < nb) {
    int i = b * 256 + threadIdx.x;
    if (i < n) {
      int c = cnt[i];
      dinv[i] = rsqrtf((float)(c + 1)); // +1 = self-loop; always > 0
      int cm = c < 32 ? c : 32;
      int cp = (cm + 7) & ~7;
      for (int k = cm; k < cp; k++) epk[(size_t)i * 32 + k] = n;  // zero row
    }
  } else {
    int e = (b - nb) * 256 + threadIdx.x;
    if (e < E) {
      int s = srcv[e], d = dstv[e];
      int r = pos[e];
      if (r < 32) {
        epk[(size_t)d * 32 + r] = s;
      } else {
        int o = atomicAdd(ovfn, 1);
        if (o < E) {                   // defensive clamp (can't exceed)
          int2 t; t.x = s; t.y = d;
          ovf[o] = t;
        }
      }
    }
  }
}

// single GEMM (layers 0,1,2 — bf16 input, LDS-staged Wt, dinv prescale)
__global__ __launch_bounds__(256, 2) void k_gemm_mfma(
    const unsigned short* __restrict__ Xb,
    const unsigned short* __restrict__ Wt,
    const float* __restrict__ bias,
    const float* __restrict__ dv,
    unsigned short* __restrict__ Y,
    int n) {
  __shared__ unsigned short sWt[128 * 128];
  stage_w(Wt, sWt);
  gemm_tile(blockIdx.x, Xb, sWt, bias, dv, Y, n);
}

// ---------------- aggregation (FINAL form — R15-proven, do not widen) ------
// R12: deeper single chain re-serialized (VGPR 36); R16: two-node spilled
// AND still pinned at 4.0 TB/s — the ~3.9-4.0 TB/s gather path is a real
// ceiling for random 256 B rows. 8-deep / VGPR-36 is the optimum.
static __device__ __forceinline__ void add8(uint4 h, float* a) {
  a[0] += bf_lo(h.x); a[1] += bf_hi(h.x);
  a[2] += bf_lo(h.y); a[3] += bf_hi(h.y);
  a[4] += bf_lo(h.z); a[5] += bf_hi(h.z);
  a[6] += bf_lo(h.w); a[7] += bf_hi(h.w);
}

__global__ __launch_bounds__(256, 4) void k_agg(
    const uint4* __restrict__ H,         // bf16x8 per lane [(n+1)*16], prescaled
    const int* __restrict__ cnt,
    const int* __restrict__ epk,
    const float* __restrict__ dinv,
    const float* __restrict__ bias,
    const uint4* __restrict__ resid,     // bf16x8 or null
    uint4* __restrict__ outb,            // bf16 out (layers 0,1) or null
    float4* __restrict__ outf,           // f32 out (layer 2) or null
    const int2* __restrict__ ovf, const int* __restrict__ ovfn,
    int n, int Ecap) {
  int node = blockIdx.x * 16 + (threadIdx.x >> 4);
  int l = threadIdx.x & 15;
  if (node >= n) return;

  int tot = cnt[node];
  int cm = tot < 32 ? tot : 32;
  int pdeg = (cm + 7) & ~7;

  uint4 hv = H[(size_t)node * 16 + l];   // self term (prescaled)
  float a[8];
  a[0] = bf_lo(hv.x); a[1] = bf_hi(hv.x);
  a[2] = bf_lo(hv.y); a[3] = bf_hi(hv.y);
  a[4] = bf_lo(hv.z); a[5] = bf_hi(hv.z);
  a[6] = bf_lo(hv.w); a[7] = bf_hi(hv.w);

  const int4* epk4 = (const int4*)(epk + (size_t)node * 32);
  for (int j = 0; j < pdeg; j += 8) {
    int4 e0 = epk4[j >> 2];
    int4 e1 = epk4[(j >> 2) + 1];
    uint4 h0 = H[(size_t)(unsigned)e0.x * 16 + l];
    uint4 h1 = H[(size_t)(unsigned)e0.y * 16 + l];
    uint4 h2 = H[(size_t)(unsigned)e0.z * 16 + l];
    uint4 h3 = H[(size_t)(unsigned)e0.w * 16 + l];
    uint4 h4 = H[(size_t)(unsigned)e1.x * 16 + l];
    uint4 h5 = H[(size_t)(unsigned)e1.y * 16 + l];
    uint4 h6 = H[(size_t)(unsigned)e1.z * 16 + l];
    uint4 h7 = H[(size_t)(unsigned)e1.w * 16 + l];
    add8(h0, a); add8(h1, a); add8(h2, a); add8(h3, a);
    add8(h4, a); add8(h5, a); add8(h6, a); add8(h7, a);
  }
  if (tot > 32) {                        // rare: walk overflow list
    int no = *ovfn;
    no = no < Ecap ? no : Ecap;          // defensive clamp
    for (int i = 0; i < no; i++) {
      int2 t = ovf[i];
      if (t.y == node) add8(H[(size_t)(unsigned)t.x * 16 + l], a);
    }
  }

  float dn = dinv[node];
  float4 bl = ((const float4*)bias)[l * 2];
  float4 bh = ((const float4*)bias)[l * 2 + 1];
  a[0] = fmaxf(fmaf(a[0], dn, bl.x), 0.f); a[1] = fmaxf(fmaf(a[1], dn, bl.y), 0.f);
  a[2] = fmaxf(fmaf(a[2], dn, bl.z), 0.f); a[3] = fmaxf(fmaf(a[3], dn, bl.w), 0.f);
  a[4] = fmaxf(fmaf(a[4], dn, bh.x), 0.f); a[5] = fmaxf(fmaf(a[5], dn, bh.y), 0.f);
  a[6] = fmaxf(fmaf(a[6], dn, bh.z), 0.f); a[7] = fmaxf(fmaf(a[7], dn, bh.w), 0.f);
  if (resid) {
    uint4 r = resid[(size_t)node * 16 + l];
    a[0] += bf_lo(r.x); a[1] += bf_hi(r.x);
    a[2] += bf_lo(r.y); a[3] += bf_hi(r.y);
    a[4] += bf_lo(r.z); a[5] += bf_hi(r.z);
    a[6] += bf_lo(r.w); a[7] += bf_hi(r.w);
  }
  if (outb) {
    uint4 o;
    o.x = pack2(a[0], a[1]); o.y = pack2(a[2], a[3]);
    o.z = pack2(a[4], a[5]); o.w = pack2(a[6], a[7]);
    outb[(size_t)node * 16 + l] = o;
  } else {
    float4 o0; o0.x = a[0]; o0.y = a[1]; o0.z = a[2]; o0.w = a[3];
    float4 o1; o1.x = a[4]; o1.y = a[5]; o1.z = a[6]; o1.w = a[7];
    outf[(size_t)node * 32 + l * 2] = o0;
    outf[(size_t)node * 32 + l * 2 + 1] = o1;
  }
}

extern "C" void kernel_launch(void* const* d_in, const int* in_sizes, int n_in,
                              void* d_out, int out_size, void* d_ws, size_t ws_size,
                              hipStream_t stream) {
  const float* x  = (const float*)d_in[0];
  const int* edges = (const int*)d_in[1];
  const float* W0 = (const float*)d_in[2];
  const float* b0 = (const float*)d_in[3];
  const float* W1 = (const float*)d_in[4];
  const float* b1 = (const float*)d_in[5];
  const float* W2 = (const float*)d_in[6];
  const float* b2 = (const float*)d_in[7];
  const float* Wr = (const float*)d_in[8];
  const float* br = (const float*)d_in[9];

  int N = in_sizes[0] / 128;
  int E = in_sizes[1] / 2;
  const int* src = edges;
  const int* dst = edges + E;

  char* ws = (char*)d_ws;
  size_t off = 0;
  auto alloc = [&](size_t bytes) -> void* {
    void* p = ws + off; off = WS_ALIGN(off + bytes); return p;
  };
  int*   cnt  = (int*)  alloc((size_t)N * 4);
  int*   ovfn = (int*)  alloc(256);     // adjacent to cnt: one memset covers both
  float* dinv = (float*)alloc((size_t)N * 4);
  int2*  ovf  = (int2*) alloc((size_t)E * 8);
  int*   epk  = (int*)  alloc((size_t)N * 32 * 4);           // fixed-stride CSR
  unsigned short* xb = (unsigned short*)alloc((size_t)N * 128 * 2);
  unsigned short* Wt = (unsigned short*)alloc((size_t)4 * 16384 * 2);
  unsigned short* A  = (unsigned short*)alloc(((size_t)N + 1) * 128 * 2); // +zero row
  unsigned short* Hb = (unsigned short*)alloc((size_t)N * 128 * 2);
  unsigned short* R  = (unsigned short*)alloc((size_t)N * 128 * 2);
  int* pos = (int*)A;   // pos[E] lives only between k_cntprep and k_scat; A
                        // is first written by gemm0, which runs after. pos
                        // (6.4 MB) does not reach A's zero row (offset 25.6 MB).
  (void)ws_size; (void)n_in; (void)out_size;

  int n4 = N * 128 / 4;
  int eb = (E + 255) / 256;
  int xbn = (n4 + 255) / 256;
  int nb = (N + 255) / 256;
  int gb = (N + 63) / 64;
  int ab = (N + 15) / 16;
  unsigned short* Wt0 = Wt;
  unsigned short* Wt1 = Wt + 16384;
  unsigned short* Wt2 = Wt + 2 * 16384;

  // ---- zeroing via memset (capture-safe; harness itself enqueues memsets) --
  hipMemsetAsync(cnt, 0, (size_t)((char*)ovfn - (char*)cnt) + 4, stream);
  hipMemsetAsync(A + (size_t)N * 128, 0, 256, stream);

  // ---- interleaved atomic count + prep + residual GEMM (%4 roles) ----
  int pb = xbn + 192;                   // prep blocks (xb + W0/1/2 transpose)
  int pbh = (pb + 1) / 2;
  int m4 = eb > pbh ? eb : pbh;
  m4 = m4 > gb ? m4 : gb;
  k_cntprep<<<4 * m4, 256, 0, stream>>>(dst, E, eb, cnt, pos,
                                        x, (unsigned*)xb, n4, xbn,
                                        W0, W1, W2, Wt, Wr, br, R, gb, N);
  // ---- aux-first scatter ----
  k_scat<<<nb + eb, 256, 0, stream>>>(src, dst, pos, E, nb, cnt, dinv,
                                      epk, ovf, ovfn, N);
  // ---- layer-0 GEMM ----
  k_gemm_mfma<<<gb, 256, 0, stream>>>(xb, Wt0, nullptr, dinv, A, N);

  // ---- GCN layers ----
  k_agg<<<ab, 256, 0, stream>>>((const uint4*)A, cnt, epk, dinv, b0,
                                (const uint4*)R, (uint4*)Hb, nullptr, ovf, ovfn, N, E);
  k_gemm_mfma<<<gb, 256, 0, stream>>>(Hb, Wt1, nullptr, dinv, A, N);
  k_agg<<<ab, 256, 0, stream>>>((const uint4*)A, cnt, epk, dinv, b1,
                                nullptr, (uint4*)R, nullptr, ovf, ovfn, N, E);
  k_gemm_mfma<<<gb, 256, 0, stream>>>(R, Wt2, nullptr, dinv, A, N);
  k_agg<<<ab, 256, 0, stream>>>((const uint4*)A, cnt, epk, dinv, b2,
                                nullptr, nullptr, (float4*)d_out, ovf, ovfn, N, E);
}